// Round 5
// baseline (576.530 us; speedup 1.0000x reference)
//
#include <hip/hip_runtime.h>
#include <hip/hip_bf16.h>
#include <math.h>

#define N_NODES 50000
#define N_EDGES 800000
// dims: IN=16, OUT=16, EF=16, H=4, HD=32, DGAT=128

__device__ inline float bf2f(unsigned short u) {
    return __builtin_bit_cast(float, (unsigned)u << 16);
}
__device__ inline float bf2f_lo(unsigned u) { return __builtin_bit_cast(float, u << 16); }
__device__ inline float bf2f_hi(unsigned u) { return __builtin_bit_cast(float, u & 0xffff0000u); }
__device__ inline unsigned short f2bf(float f) {
    __hip_bfloat16 h = __float2bfloat16(f);
    return __builtin_bit_cast(unsigned short, h);
}

// ---------------- graph build: degree count (both directions) ----------------
__global__ void count_kernel(const int* __restrict__ src, const int* __restrict__ dst,
                             int* __restrict__ cd, int* __restrict__ cs) {
    int e = blockIdx.x * 256 + threadIdx.x;
    if (e < N_EDGES) {
        atomicAdd(&cd[dst[e]], 1);
        atomicAdd(&cs[src[e]], 1);
    }
}

__global__ void scan_kernel(const int* __restrict__ counts, int* __restrict__ offsets) {
    __shared__ int sdata[1024];
    int tid = threadIdx.x;
    const int chunk = (N_NODES + 1023) / 1024;
    int beg = tid * chunk;
    int end = min(beg + chunk, N_NODES);
    int s = 0;
    for (int j = beg; j < end; ++j) s += counts[j];
    sdata[tid] = s;
    __syncthreads();
    for (int d = 1; d < 1024; d <<= 1) {
        int v = (tid >= d) ? sdata[tid - d] : 0;
        __syncthreads();
        sdata[tid] += v;
        __syncthreads();
    }
    int base = (tid == 0) ? 0 : sdata[tid - 1];
    for (int j = beg; j < end; ++j) { offsets[j] = base; base += counts[j]; }
    if (tid == 0) offsets[N_NODES] = sdata[1023];
}

// one pass: dst-CSR position for each edge, plus src-CSC slot -> (eid, dst_pos)
__global__ void scatter_kernel(const int* __restrict__ src, const int* __restrict__ dst,
                               const int* __restrict__ offd, const int* __restrict__ offs,
                               int* __restrict__ curd, int* __restrict__ curs,
                               int* __restrict__ csr_src, int* __restrict__ csc_eid,
                               int* __restrict__ csc_pos) {
    int e = blockIdx.x * 256 + threadIdx.x;
    if (e < N_EDGES) {
        int d = dst[e], s = src[e];
        int pos = offd[d] + atomicAdd(&curd[d], 1);
        csr_src[pos] = s;
        int spos = offs[s] + atomicAdd(&curs[s], 1);
        csc_eid[spos] = e;
        csc_pos[spos] = pos;
    }
}

// ---------------- node-level precompute, TRANSPOSED: yT[n][o][f] ----------------
// yT[n][o*16+f] = bf16( sum_i x[n,i] * Wnn[f*256 + i*16 + o] ), t[n][o] = x . bnn[:,o]
// lane owns (o = lane>>2, f-quad = (lane&3)*4) -> ushort4 store is contiguous.
__global__ __launch_bounds__(256) void y_kernel(const float* __restrict__ x,
                                                const float* __restrict__ Wnn,
                                                const float* __restrict__ bnn,
                                                unsigned short* __restrict__ yT,
                                                float* __restrict__ t_arr) {
    int tid = threadIdx.x;
    int n = blockIdx.x * 4 + (tid >> 6);
    int lane = tid & 63;
    if (n >= N_NODES) return;
    int o = lane >> 2;
    int fq = (lane & 3) * 4;
    const float* xr = x + (size_t)n * 16;
    float xv[16];
#pragma unroll
    for (int q = 0; q < 4; ++q) {
        float4 x4 = *(const float4*)(xr + q * 4);
        xv[4 * q + 0] = x4.x; xv[4 * q + 1] = x4.y; xv[4 * q + 2] = x4.z; xv[4 * q + 3] = x4.w;
    }
    float a0 = 0.f, a1 = 0.f, a2 = 0.f, a3 = 0.f;
#pragma unroll
    for (int i = 0; i < 16; ++i) {
        float xi = xv[i];
        a0 = fmaf(xi, Wnn[(fq + 0) * 256 + i * 16 + o], a0);
        a1 = fmaf(xi, Wnn[(fq + 1) * 256 + i * 16 + o], a1);
        a2 = fmaf(xi, Wnn[(fq + 2) * 256 + i * 16 + o], a2);
        a3 = fmaf(xi, Wnn[(fq + 3) * 256 + i * 16 + o], a3);
    }
    ushort4 o4;
    o4.x = f2bf(a0); o4.y = f2bf(a1); o4.z = f2bf(a2); o4.w = f2bf(a3);
    *(ushort4*)(yT + (size_t)n * 256 + o * 16 + fq) = o4;
    if (lane < 16) {
        float tv = 0.f;
#pragma unroll
        for (int i = 0; i < 16; ++i) tv = fmaf(xv[i], bnn[i * 16 + lane], tv);
        t_arr[(size_t)n * 16 + lane] = tv;
    }
}

// ---------------- msg in src order: msg[pos][o] = t[s][o] + sum_f ea[eid][f]*yT[s][o][f] ----------------
// Wave per src-chunk; y row loaded ONCE per src (lane o holds its 16 f-values in regs).
// 4 edges per step (sub = lane>>4); ea gathered 64B/edge; indices preloaded 64-ahead;
// ea load 2-stage pipelined. msg scattered to dst-CSR slot (64B rows).
#define NN_BLOCKS 2048
#define NN_WAVES (NN_BLOCKS * 4)
__global__ __launch_bounds__(256) void msg_kernel(
    const unsigned short* __restrict__ yT, const float* __restrict__ t_arr,
    const float* __restrict__ ea, const int* __restrict__ csc_eid,
    const int* __restrict__ csc_pos, const int* __restrict__ offs,
    float* __restrict__ msg)
{
    const int wid = threadIdx.x >> 6, lane = threadIdx.x & 63;
    const int o = lane & 15, sub = lane >> 4;
    const int wgid = blockIdx.x * 4 + wid;
    const int per = (N_NODES + NN_WAVES - 1) / NN_WAVES;
    const int n0 = wgid * per;
    const int n1 = min(n0 + per, N_NODES);
    for (int s = n0; s < n1; ++s) {
        const int beg = offs[s], end = offs[s + 1];
        if (beg == end) continue;
        const unsigned short* yp = yT + (size_t)s * 256 + o * 16;
        uint4 r0 = *(const uint4*)yp;
        uint4 r1 = *(const uint4*)(yp + 8);
        float yv[16];
        yv[0]  = bf2f_lo(r0.x); yv[1]  = bf2f_hi(r0.x);
        yv[2]  = bf2f_lo(r0.y); yv[3]  = bf2f_hi(r0.y);
        yv[4]  = bf2f_lo(r0.z); yv[5]  = bf2f_hi(r0.z);
        yv[6]  = bf2f_lo(r0.w); yv[7]  = bf2f_hi(r0.w);
        yv[8]  = bf2f_lo(r1.x); yv[9]  = bf2f_hi(r1.x);
        yv[10] = bf2f_lo(r1.y); yv[11] = bf2f_hi(r1.y);
        yv[12] = bf2f_lo(r1.z); yv[13] = bf2f_hi(r1.z);
        yv[14] = bf2f_lo(r1.w); yv[15] = bf2f_hi(r1.w);
        float t_o = t_arr[(size_t)s * 16 + o];
        for (int base = beg; base < end; base += 64) {
            int cnt = min(end - base, 64);
            int e_l = 0, p_l = 0;
            if (lane < cnt) { e_l = csc_eid[base + lane]; p_l = csc_pos[base + lane]; }
            int idx = sub;
            int eid = __shfl(e_l, idx, 64);
            int pos = __shfl(p_l, idx, 64);
            bool v = idx < cnt;
            float av = v ? ea[(size_t)eid * 16 + o] : 0.f;
            for (int idx0 = 0; idx0 < cnt; idx0 += 4) {
                float avc = av; int posc = pos; bool vc = v;
                if (idx0 + 4 < cnt) {
                    idx = idx0 + 4 + sub;
                    eid = __shfl(e_l, idx, 64);
                    pos = __shfl(p_l, idx, 64);
                    v = idx < cnt;
                    av = v ? ea[(size_t)eid * 16 + o] : 0.f;
                }
                float m = t_o;
#pragma unroll
                for (int f = 0; f < 16; ++f)
                    m = fmaf(__shfl(avc, (lane & 48) + f, 64), yv[f], m);
                if (vc) msg[(size_t)posc * 16 + o] = m;
            }
        }
    }
}

// ---------------- NNConv aggregate (streams msg) + root + relu ----------------
__global__ __launch_bounds__(256) void aggregate_kernel(const float* __restrict__ msg,
                                                        const int* __restrict__ offd,
                                                        const float* __restrict__ x,
                                                        const float* __restrict__ Wroot,
                                                        const float* __restrict__ becc,
                                                        float* __restrict__ h) {
    int t = blockIdx.x * 256 + threadIdx.x;
    int n = t >> 4;
    int o = t & 15;
    if (n >= N_NODES) return;
    int beg = offd[n], end = offd[n + 1];
    float acc = 0.f;
    int j = beg;
    for (; j + 4 <= end; j += 4) {
        acc += msg[(size_t)(j + 0) * 16 + o];
        acc += msg[(size_t)(j + 1) * 16 + o];
        acc += msg[(size_t)(j + 2) * 16 + o];
        acc += msg[(size_t)(j + 3) * 16 + o];
    }
    for (; j < end; ++j) acc += msg[(size_t)j * 16 + o];
    float r = becc[o];
#pragma unroll
    for (int i = 0; i < 16; ++i) r = fmaf(x[(size_t)n * 16 + i], Wroot[i * 16 + o], r);
    h[(size_t)n * 16 + o] = fmaxf(acc + r, 0.f);
}

// ---------------- GAT projection: z(bf16), es, ed ----------------
__global__ void z_kernel(const float* __restrict__ h, const float* __restrict__ Wgat,
                         const float* __restrict__ asrc, const float* __restrict__ adst,
                         unsigned short* __restrict__ z_bf, float* __restrict__ es,
                         float* __restrict__ ed) {
    int n = blockIdx.x * 2 + (threadIdx.x >> 7);
    int d = threadIdx.x & 127;
    if (n >= N_NODES) return;
    float acc = 0.f;
#pragma unroll
    for (int i = 0; i < 16; ++i) acc = fmaf(h[(size_t)n * 16 + i], Wgat[i * 128 + d], acc);
    z_bf[(size_t)n * 128 + d] = f2bf(acc);
    float ps = acc * asrc[d];
    float pd = acc * adst[d];
    for (int k = 16; k > 0; k >>= 1) {
        ps += __shfl_down(ps, k, 32);
        pd += __shfl_down(pd, k, 32);
    }
    if ((d & 31) == 0) {
        int head = d >> 5;
        es[(size_t)n * 4 + head] = ps;
        ed[(size_t)n * 4 + head] = pd;
    }
}

// ---------------- GAT aggregation + bias + relu + final fc (4-wide unroll) ----------------
__global__ void gat_kernel(const unsigned short* __restrict__ z_bf, const float* __restrict__ es,
                           const float* __restrict__ ed, const int* __restrict__ csr_src,
                           const int* __restrict__ offd,
                           const float* __restrict__ bgat, const float* __restrict__ Wfc,
                           const float* __restrict__ bfc, float* __restrict__ out) {
    int wid = threadIdx.x >> 6;
    int lane = threadIdx.x & 63;
    int n = blockIdx.x * 4 + wid;
    if (n >= N_NODES) return;
    int head = lane >> 4;
    float edh = ed[(size_t)n * 4 + head];
    int beg = offd[n], end = offd[n + 1];
    int deg = end - beg;
    float den = 0.f, a0 = 0.f, a1 = 0.f;
    int s_l = (lane < deg) ? csr_src[beg + lane] : 0;
    int m64 = min(deg, 64);
    int el = 0;
    for (; el + 4 <= m64; el += 4) {
        int s0 = __shfl(s_l, el + 0, 64);
        int s1 = __shfl(s_l, el + 1, 64);
        int s2 = __shfl(s_l, el + 2, 64);
        int s3 = __shfl(s_l, el + 3, 64);
        float l0 = es[(size_t)s0 * 4 + head] + edh;
        float l1 = es[(size_t)s1 * 4 + head] + edh;
        float l2 = es[(size_t)s2 * 4 + head] + edh;
        float l3 = es[(size_t)s3 * 4 + head] + edh;
        l0 = (l0 > 0.f) ? l0 : 0.2f * l0;
        l1 = (l1 > 0.f) ? l1 : 0.2f * l1;
        l2 = (l2 > 0.f) ? l2 : 0.2f * l2;
        l3 = (l3 > 0.f) ? l3 : 0.2f * l3;
        float w0 = __expf(l0), w1 = __expf(l1), w2 = __expf(l2), w3 = __expf(l3);
        ushort2 z0 = *(const ushort2*)(z_bf + (size_t)s0 * 128 + 2 * lane);
        ushort2 z1 = *(const ushort2*)(z_bf + (size_t)s1 * 128 + 2 * lane);
        ushort2 z2 = *(const ushort2*)(z_bf + (size_t)s2 * 128 + 2 * lane);
        ushort2 z3 = *(const ushort2*)(z_bf + (size_t)s3 * 128 + 2 * lane);
        den += (w0 + w1) + (w2 + w3);
        a0 = fmaf(w0, bf2f(z0.x), a0); a1 = fmaf(w0, bf2f(z0.y), a1);
        a0 = fmaf(w1, bf2f(z1.x), a0); a1 = fmaf(w1, bf2f(z1.y), a1);
        a0 = fmaf(w2, bf2f(z2.x), a0); a1 = fmaf(w2, bf2f(z2.y), a1);
        a0 = fmaf(w3, bf2f(z3.x), a0); a1 = fmaf(w3, bf2f(z3.y), a1);
    }
    for (; el < m64; ++el) {
        int s = __shfl(s_l, el, 64);
        float l = es[(size_t)s * 4 + head] + edh;
        l = (l > 0.f) ? l : 0.2f * l;
        float w = __expf(l);
        den += w;
        ushort2 zv = *(const ushort2*)(z_bf + (size_t)s * 128 + 2 * lane);
        a0 = fmaf(w, bf2f(zv.x), a0);
        a1 = fmaf(w, bf2f(zv.y), a1);
    }
    for (int j = beg + 64; j < end; ++j) {
        int s = csr_src[j];
        float l = es[(size_t)s * 4 + head] + edh;
        l = (l > 0.f) ? l : 0.2f * l;
        float w = __expf(l);
        den += w;
        ushort2 zv = *(const ushort2*)(z_bf + (size_t)s * 128 + 2 * lane);
        a0 = fmaf(w, bf2f(zv.x), a0);
        a1 = fmaf(w, bf2f(zv.y), a1);
    }
    float inv = 1.f / (den + 1e-16f);
    float2 bg = *(const float2*)(bgat + 2 * lane);
    float g0 = fmaxf(fmaf(a0, inv, bg.x), 0.f);
    float g1 = fmaxf(fmaf(a1, inv, bg.y), 0.f);
    float2 wf = *(const float2*)(Wfc + 2 * lane);
    float p = g0 * wf.x + g1 * wf.y;
    for (int k = 32; k > 0; k >>= 1) p += __shfl_down(p, k, 64);
    if (lane == 0) out[n] = p + bfc[0];
}

extern "C" void kernel_launch(void* const* d_in, const int* in_sizes, int n_in,
                              void* d_out, int out_size, void* d_ws, size_t ws_size,
                              hipStream_t stream) {
    const float* x     = (const float*)d_in[0];
    const int*   eidx  = (const int*)d_in[1];
    const float* ea    = (const float*)d_in[2];
    const float* Wnn   = (const float*)d_in[3];
    const float* bnn   = (const float*)d_in[4];
    const float* Wroot = (const float*)d_in[5];
    const float* becc  = (const float*)d_in[6];
    const float* Wgat  = (const float*)d_in[7];
    const float* asrc  = (const float*)d_in[8];
    const float* adst  = (const float*)d_in[9];
    const float* bgat  = (const float*)d_in[10];
    const float* Wfc   = (const float*)d_in[11];
    const float* bfc   = (const float*)d_in[12];
    const int* src = eidx;
    const int* dst = eidx + N_EDGES;
    float* out = (float*)d_out;

    char* ws = (char*)d_ws;
    size_t off = 0;
    auto alloc = [&](size_t bytes) {
        void* p = ws + off;
        off += (bytes + 255) & ~(size_t)255;
        return p;
    };
    int* cd      = (int*)alloc((size_t)N_NODES * 4);
    int* cs      = (int*)alloc((size_t)N_NODES * 4);
    int* curd    = (int*)alloc((size_t)N_NODES * 4);
    int* curs    = (int*)alloc((size_t)N_NODES * 4);
    int* offd    = (int*)alloc((size_t)(N_NODES + 1) * 4);
    int* offs    = (int*)alloc((size_t)(N_NODES + 1) * 4);
    int* csr_src = (int*)alloc((size_t)N_EDGES * 4);
    int* csc_eid = (int*)alloc((size_t)N_EDGES * 4);
    int* csc_pos = (int*)alloc((size_t)N_EDGES * 4);
    unsigned short* yT = (unsigned short*)alloc((size_t)N_NODES * 256 * 2);
    float* t_arr = (float*)alloc((size_t)N_NODES * 16 * 4);
    float* msg   = (float*)alloc((size_t)N_EDGES * 16 * 4);
    float* h     = (float*)alloc((size_t)N_NODES * 16 * 4);
    unsigned short* z_bf = (unsigned short*)alloc((size_t)N_NODES * 128 * 2);
    float* es    = (float*)alloc((size_t)N_NODES * 4 * 4);
    float* ed    = (float*)alloc((size_t)N_NODES * 4 * 4);

    hipMemsetAsync(cd, 0, (size_t)N_NODES * 4, stream);
    hipMemsetAsync(cs, 0, (size_t)N_NODES * 4, stream);
    hipMemsetAsync(curd, 0, (size_t)N_NODES * 4, stream);
    hipMemsetAsync(curs, 0, (size_t)N_NODES * 4, stream);

    int eb = (N_EDGES + 255) / 256;
    count_kernel<<<eb, 256, 0, stream>>>(src, dst, cd, cs);
    scan_kernel<<<1, 1024, 0, stream>>>(cd, offd);
    scan_kernel<<<1, 1024, 0, stream>>>(cs, offs);
    scatter_kernel<<<eb, 256, 0, stream>>>(src, dst, offd, offs, curd, curs,
                                           csr_src, csc_eid, csc_pos);
    y_kernel<<<(N_NODES + 3) / 4, 256, 0, stream>>>(x, Wnn, bnn, yT, t_arr);
    msg_kernel<<<NN_BLOCKS, 256, 0, stream>>>(yT, t_arr, ea, csc_eid, csc_pos, offs, msg);
    aggregate_kernel<<<(N_NODES * 16 + 255) / 256, 256, 0, stream>>>(msg, offd, x, Wroot, becc, h);
    z_kernel<<<(N_NODES + 1) / 2, 256, 0, stream>>>(h, Wgat, asrc, adst, z_bf, es, ed);
    gat_kernel<<<(N_NODES + 3) / 4, 256, 0, stream>>>(z_bf, es, ed, csr_src, offd, bgat, Wfc, bfc, out);
}

// Round 6
// 388.017 us; speedup vs baseline: 1.4858x; 1.4858x over previous
//
#include <hip/hip_runtime.h>
#include <hip/hip_bf16.h>
#include <math.h>

#define N_NODES 50000
#define N_EDGES 800000
// dims: IN=16, OUT=16, EF=16, H=4, HD=32, DGAT=128

__device__ inline float bf2f(unsigned short u) {
    return __builtin_bit_cast(float, (unsigned)u << 16);
}
__device__ inline float bf2f_lo(unsigned u) { return __builtin_bit_cast(float, u << 16); }
__device__ inline float bf2f_hi(unsigned u) { return __builtin_bit_cast(float, u & 0xffff0000u); }
__device__ inline unsigned short f2bf(float f) {
    __hip_bfloat16 h = __float2bfloat16(f);
    return __builtin_bit_cast(unsigned short, h);
}

// ---------------- graph build ----------------
__global__ void count_kernel(const int* __restrict__ dst, int* __restrict__ cd) {
    int e = blockIdx.x * 256 + threadIdx.x;
    if (e < N_EDGES) atomicAdd(&cd[dst[e]], 1);
}

__global__ void scan_kernel(const int* __restrict__ counts, int* __restrict__ offsets) {
    __shared__ int sdata[1024];
    int tid = threadIdx.x;
    const int chunk = (N_NODES + 1023) / 1024;
    int beg = tid * chunk;
    int end = min(beg + chunk, N_NODES);
    int s = 0;
    for (int j = beg; j < end; ++j) s += counts[j];
    sdata[tid] = s;
    __syncthreads();
    for (int d = 1; d < 1024; d <<= 1) {
        int v = (tid >= d) ? sdata[tid - d] : 0;
        __syncthreads();
        sdata[tid] += v;
        __syncthreads();
    }
    int base = (tid == 0) ? 0 : sdata[tid - 1];
    for (int j = beg; j < end; ++j) { offsets[j] = base; base += counts[j]; }
    if (tid == 0) offsets[N_NODES] = sdata[1023];
}

// single packed 8B write per edge: csr[pos] = {src, eid}
__global__ void scatter_kernel(const int* __restrict__ src, const int* __restrict__ dst,
                               const int* __restrict__ offd, int* __restrict__ curd,
                               int2* __restrict__ csr) {
    int e = blockIdx.x * 256 + threadIdx.x;
    if (e < N_EDGES) {
        int d = dst[e];
        int pos = offd[d] + atomicAdd(&curd[d], 1);
        csr[pos] = make_int2(src[e], e);
    }
}

// ---------------- node-level precompute, TRANSPOSED: yT[n][o][f] ----------------
// yT[n][o*16+f] = bf16( sum_i x[n,i] * Wnn[f*256 + i*16 + o] ), t[n][o] = x . bnn[:,o]
__global__ __launch_bounds__(256) void y_kernel(const float* __restrict__ x,
                                                const float* __restrict__ Wnn,
                                                const float* __restrict__ bnn,
                                                unsigned short* __restrict__ yT,
                                                float* __restrict__ t_arr) {
    int tid = threadIdx.x;
    int n = blockIdx.x * 4 + (tid >> 6);
    int lane = tid & 63;
    if (n >= N_NODES) return;
    int o = lane >> 2;
    int fq = (lane & 3) * 4;
    const float* xr = x + (size_t)n * 16;
    float xv[16];
#pragma unroll
    for (int q = 0; q < 4; ++q) {
        float4 x4 = *(const float4*)(xr + q * 4);
        xv[4 * q + 0] = x4.x; xv[4 * q + 1] = x4.y; xv[4 * q + 2] = x4.z; xv[4 * q + 3] = x4.w;
    }
    float a0 = 0.f, a1 = 0.f, a2 = 0.f, a3 = 0.f;
#pragma unroll
    for (int i = 0; i < 16; ++i) {
        float xi = xv[i];
        a0 = fmaf(xi, Wnn[(fq + 0) * 256 + i * 16 + o], a0);
        a1 = fmaf(xi, Wnn[(fq + 1) * 256 + i * 16 + o], a1);
        a2 = fmaf(xi, Wnn[(fq + 2) * 256 + i * 16 + o], a2);
        a3 = fmaf(xi, Wnn[(fq + 3) * 256 + i * 16 + o], a3);
    }
    ushort4 o4;
    o4.x = f2bf(a0); o4.y = f2bf(a1); o4.z = f2bf(a2); o4.w = f2bf(a3);
    *(ushort4*)(yT + (size_t)n * 256 + o * 16 + fq) = o4;
    if (lane < 16) {
        float tv = 0.f;
#pragma unroll
        for (int i = 0; i < 16; ++i) tv = fmaf(xv[i], bnn[i * 16 + lane], tv);
        t_arr[(size_t)n * 16 + lane] = tv;
    }
}

// ---------------- fused NNConv aggregate + root + relu + GAT projection ----------------
// ONE WAVE PER NODE (no persistent loop): latency hidden by TLP. Lane = (sub, o):
// 4 edges/step; per edge gather ea[eid] (16 lanes, 64B) and yT[s] row (2x16B/lane),
// shfl-broadcast ea[f] across the sub-group; acc[o] in-register; then h, z, es/ed in-wave.
__global__ __launch_bounds__(256) void fused_kernel(
    const float* __restrict__ x, const unsigned short* __restrict__ yT,
    const float* __restrict__ t_arr, const float* __restrict__ ea,
    const int2* __restrict__ csr, const int* __restrict__ offd,
    const float* __restrict__ Wroot, const float* __restrict__ becc,
    const float* __restrict__ Wgat, const float* __restrict__ asrc,
    const float* __restrict__ adst,
    unsigned short* __restrict__ z_bf, float* __restrict__ es, float* __restrict__ ed)
{
    const int wid = threadIdx.x >> 6, lane = threadIdx.x & 63;
    const int n = blockIdx.x * 4 + wid;
    if (n >= N_NODES) return;
    const int o = lane & 15, sub = lane >> 4;
    const int beg = offd[n], end = offd[n + 1];
    float acc = 0.f;
    for (int base = beg; base < end; base += 64) {
        int cnt = min(end - base, 64);
        int2 pr = make_int2(0, 0);
        if (lane < cnt) pr = csr[base + lane];
        for (int idx0 = 0; idx0 < cnt; idx0 += 4) {
            int idx = idx0 + sub;                 // uniform within 16-lane sub-group
            int s   = __shfl(pr.x, idx, 64);
            int eid = __shfl(pr.y, idx, 64);
            bool v = idx < cnt;
            float av = v ? ea[(size_t)eid * 16 + o] : 0.f;
            float tv = v ? t_arr[(size_t)s * 16 + o] : 0.f;
            const unsigned short* yp = yT + (size_t)s * 256 + o * 16;
            uint4 r0 = *(const uint4*)yp;
            uint4 r1 = *(const uint4*)(yp + 8);
            float yv[16];
            yv[0]  = bf2f_lo(r0.x); yv[1]  = bf2f_hi(r0.x);
            yv[2]  = bf2f_lo(r0.y); yv[3]  = bf2f_hi(r0.y);
            yv[4]  = bf2f_lo(r0.z); yv[5]  = bf2f_hi(r0.z);
            yv[6]  = bf2f_lo(r0.w); yv[7]  = bf2f_hi(r0.w);
            yv[8]  = bf2f_lo(r1.x); yv[9]  = bf2f_hi(r1.x);
            yv[10] = bf2f_lo(r1.y); yv[11] = bf2f_hi(r1.y);
            yv[12] = bf2f_lo(r1.z); yv[13] = bf2f_hi(r1.z);
            yv[14] = bf2f_lo(r1.w); yv[15] = bf2f_hi(r1.w);
            float m = tv;
#pragma unroll
            for (int f = 0; f < 16; ++f)
                m = fmaf(__shfl(av, (lane & 48) + f, 64), yv[f], m);
            acc += m;   // m == 0 for invalid edges (av, tv zeroed wave-uniformly per sub)
        }
    }
    // reduce across the 4 sub-groups (same o)
    acc += __shfl_xor(acc, 16, 64);
    acc += __shfl_xor(acc, 32, 64);
    // root weight + bias + relu
    const float* xr = x + (size_t)n * 16;
    float r = becc[o];
#pragma unroll
    for (int i = 0; i < 16; ++i) r = fmaf(xr[i], Wroot[i * 16 + o], r);
    float hval = fmaxf(acc + r, 0.f);
    // z = h @ Wgat (dims lane, lane+64); h[i] broadcast from own sub-group
    float z0 = 0.f, z1 = 0.f;
#pragma unroll
    for (int i = 0; i < 16; ++i) {
        float hv = __shfl(hval, (lane & 48) + i, 64);
        z0 = fmaf(hv, Wgat[i * 128 + lane], z0);
        z1 = fmaf(hv, Wgat[i * 128 + 64 + lane], z1);
    }
    z_bf[(size_t)n * 128 + lane] = f2bf(z0);
    z_bf[(size_t)n * 128 + 64 + lane] = f2bf(z1);
    // es/ed per-head reductions
    float p0s = z0 * asrc[lane], p1s = z1 * asrc[lane + 64];
    float p0d = z0 * adst[lane], p1d = z1 * adst[lane + 64];
#pragma unroll
    for (int k = 1; k <= 16; k <<= 1) {
        p0s += __shfl_xor(p0s, k, 64);
        p1s += __shfl_xor(p1s, k, 64);
        p0d += __shfl_xor(p0d, k, 64);
        p1d += __shfl_xor(p1d, k, 64);
    }
    if ((lane & 31) == 0) {
        int hh = lane >> 5;
        es[(size_t)n * 4 + hh]     = p0s;
        es[(size_t)n * 4 + hh + 2] = p1s;
        ed[(size_t)n * 4 + hh]     = p0d;
        ed[(size_t)n * 4 + hh + 2] = p1d;
    }
}

// ---------------- GAT aggregation + bias + relu + final fc (4-wide unroll) ----------------
__global__ void gat_kernel(const unsigned short* __restrict__ z_bf, const float* __restrict__ es,
                           const float* __restrict__ ed, const int2* __restrict__ csr,
                           const int* __restrict__ offd,
                           const float* __restrict__ bgat, const float* __restrict__ Wfc,
                           const float* __restrict__ bfc, float* __restrict__ out) {
    int wid = threadIdx.x >> 6;
    int lane = threadIdx.x & 63;
    int n = blockIdx.x * 4 + wid;
    if (n >= N_NODES) return;
    int head = lane >> 4;
    float edh = ed[(size_t)n * 4 + head];
    int beg = offd[n], end = offd[n + 1];
    int deg = end - beg;
    float den = 0.f, a0 = 0.f, a1 = 0.f;
    int s_l = (lane < deg) ? csr[beg + lane].x : 0;
    int m64 = min(deg, 64);
    int el = 0;
    for (; el + 4 <= m64; el += 4) {
        int s0 = __shfl(s_l, el + 0, 64);
        int s1 = __shfl(s_l, el + 1, 64);
        int s2 = __shfl(s_l, el + 2, 64);
        int s3 = __shfl(s_l, el + 3, 64);
        float l0 = es[(size_t)s0 * 4 + head] + edh;
        float l1 = es[(size_t)s1 * 4 + head] + edh;
        float l2 = es[(size_t)s2 * 4 + head] + edh;
        float l3 = es[(size_t)s3 * 4 + head] + edh;
        l0 = (l0 > 0.f) ? l0 : 0.2f * l0;
        l1 = (l1 > 0.f) ? l1 : 0.2f * l1;
        l2 = (l2 > 0.f) ? l2 : 0.2f * l2;
        l3 = (l3 > 0.f) ? l3 : 0.2f * l3;
        float w0 = __expf(l0), w1 = __expf(l1), w2 = __expf(l2), w3 = __expf(l3);
        ushort2 z0 = *(const ushort2*)(z_bf + (size_t)s0 * 128 + 2 * lane);
        ushort2 z1 = *(const ushort2*)(z_bf + (size_t)s1 * 128 + 2 * lane);
        ushort2 z2 = *(const ushort2*)(z_bf + (size_t)s2 * 128 + 2 * lane);
        ushort2 z3 = *(const ushort2*)(z_bf + (size_t)s3 * 128 + 2 * lane);
        den += (w0 + w1) + (w2 + w3);
        a0 = fmaf(w0, bf2f(z0.x), a0); a1 = fmaf(w0, bf2f(z0.y), a1);
        a0 = fmaf(w1, bf2f(z1.x), a0); a1 = fmaf(w1, bf2f(z1.y), a1);
        a0 = fmaf(w2, bf2f(z2.x), a0); a1 = fmaf(w2, bf2f(z2.y), a1);
        a0 = fmaf(w3, bf2f(z3.x), a0); a1 = fmaf(w3, bf2f(z3.y), a1);
    }
    for (; el < m64; ++el) {
        int s = __shfl(s_l, el, 64);
        float l = es[(size_t)s * 4 + head] + edh;
        l = (l > 0.f) ? l : 0.2f * l;
        float w = __expf(l);
        den += w;
        ushort2 zv = *(const ushort2*)(z_bf + (size_t)s * 128 + 2 * lane);
        a0 = fmaf(w, bf2f(zv.x), a0);
        a1 = fmaf(w, bf2f(zv.y), a1);
    }
    for (int j = beg + 64; j < end; ++j) {
        int s = csr[j].x;
        float l = es[(size_t)s * 4 + head] + edh;
        l = (l > 0.f) ? l : 0.2f * l;
        float w = __expf(l);
        den += w;
        ushort2 zv = *(const ushort2*)(z_bf + (size_t)s * 128 + 2 * lane);
        a0 = fmaf(w, bf2f(zv.x), a0);
        a1 = fmaf(w, bf2f(zv.y), a1);
    }
    float inv = 1.f / (den + 1e-16f);
    float2 bg = *(const float2*)(bgat + 2 * lane);
    float g0 = fmaxf(fmaf(a0, inv, bg.x), 0.f);
    float g1 = fmaxf(fmaf(a1, inv, bg.y), 0.f);
    float2 wf = *(const float2*)(Wfc + 2 * lane);
    float p = g0 * wf.x + g1 * wf.y;
    for (int k = 32; k > 0; k >>= 1) p += __shfl_down(p, k, 64);
    if (lane == 0) out[n] = p + bfc[0];
}

extern "C" void kernel_launch(void* const* d_in, const int* in_sizes, int n_in,
                              void* d_out, int out_size, void* d_ws, size_t ws_size,
                              hipStream_t stream) {
    const float* x     = (const float*)d_in[0];
    const int*   eidx  = (const int*)d_in[1];
    const float* ea    = (const float*)d_in[2];
    const float* Wnn   = (const float*)d_in[3];
    const float* bnn   = (const float*)d_in[4];
    const float* Wroot = (const float*)d_in[5];
    const float* becc  = (const float*)d_in[6];
    const float* Wgat  = (const float*)d_in[7];
    const float* asrc  = (const float*)d_in[8];
    const float* adst  = (const float*)d_in[9];
    const float* bgat  = (const float*)d_in[10];
    const float* Wfc   = (const float*)d_in[11];
    const float* bfc   = (const float*)d_in[12];
    const int* src = eidx;
    const int* dst = eidx + N_EDGES;
    float* out = (float*)d_out;

    char* ws = (char*)d_ws;
    size_t off = 0;
    auto alloc = [&](size_t bytes) {
        void* p = ws + off;
        off += (bytes + 255) & ~(size_t)255;
        return p;
    };
    int*  cd   = (int*)alloc((size_t)N_NODES * 4);
    int*  curd = (int*)alloc((size_t)N_NODES * 4);
    int*  offd = (int*)alloc((size_t)(N_NODES + 1) * 4);
    int2* csr  = (int2*)alloc((size_t)N_EDGES * 8);
    unsigned short* yT = (unsigned short*)alloc((size_t)N_NODES * 256 * 2);
    float* t_arr = (float*)alloc((size_t)N_NODES * 16 * 4);
    unsigned short* z_bf = (unsigned short*)alloc((size_t)N_NODES * 128 * 2);
    float* es = (float*)alloc((size_t)N_NODES * 4 * 4);
    float* ed = (float*)alloc((size_t)N_NODES * 4 * 4);

    hipMemsetAsync(cd, 0, (size_t)N_NODES * 4, stream);
    hipMemsetAsync(curd, 0, (size_t)N_NODES * 4, stream);

    int eb = (N_EDGES + 255) / 256;
    count_kernel<<<eb, 256, 0, stream>>>(dst, cd);
    scan_kernel<<<1, 1024, 0, stream>>>(cd, offd);
    scatter_kernel<<<eb, 256, 0, stream>>>(src, dst, offd, curd, csr);
    y_kernel<<<(N_NODES + 3) / 4, 256, 0, stream>>>(x, Wnn, bnn, yT, t_arr);
    fused_kernel<<<(N_NODES + 3) / 4, 256, 0, stream>>>(x, yT, t_arr, ea, csr, offd,
                                                        Wroot, becc, Wgat, asrc, adst,
                                                        z_bf, es, ed);
    gat_kernel<<<(N_NODES + 3) / 4, 256, 0, stream>>>(z_bf, es, ed, csr, offd,
                                                      bgat, Wfc, bfc, out);
}

// Round 7
// 297.285 us; speedup vs baseline: 1.9393x; 1.3052x over previous
//
#include <hip/hip_runtime.h>
#include <hip/hip_bf16.h>
#include <math.h>

#define N_NODES 50000
#define N_EDGES 800000
// dims: IN=16, OUT=16, EF=16, H=4, HD=32, DGAT=128

__device__ inline float bf2f(unsigned short u) {
    return __builtin_bit_cast(float, (unsigned)u << 16);
}
__device__ inline float bf2f_lo(unsigned u) { return __builtin_bit_cast(float, u << 16); }
__device__ inline float bf2f_hi(unsigned u) { return __builtin_bit_cast(float, u & 0xffff0000u); }
__device__ inline unsigned short f2bf(float f) {
    __hip_bfloat16 h = __float2bfloat16(f);
    return __builtin_bit_cast(unsigned short, h);
}

// ---------------- graph build ----------------
__global__ void count_kernel(const int* __restrict__ dst, int* __restrict__ cd) {
    int e = blockIdx.x * 256 + threadIdx.x;
    if (e < N_EDGES) atomicAdd(&cd[dst[e]], 1);
}

__global__ void scan_kernel(const int* __restrict__ counts, int* __restrict__ offsets) {
    __shared__ int sdata[1024];
    int tid = threadIdx.x;
    const int chunk = (N_NODES + 1023) / 1024;
    int beg = tid * chunk;
    int end = min(beg + chunk, N_NODES);
    int s = 0;
    for (int j = beg; j < end; ++j) s += counts[j];
    sdata[tid] = s;
    __syncthreads();
    for (int d = 1; d < 1024; d <<= 1) {
        int v = (tid >= d) ? sdata[tid - d] : 0;
        __syncthreads();
        sdata[tid] += v;
        __syncthreads();
    }
    int base = (tid == 0) ? 0 : sdata[tid - 1];
    for (int j = beg; j < end; ++j) { offsets[j] = base; base += counts[j]; }
    if (tid == 0) offsets[N_NODES] = sdata[1023];
}

// single packed 8B write per edge: csr[pos] = {src, eid}
__global__ void scatter_kernel(const int* __restrict__ src, const int* __restrict__ dst,
                               const int* __restrict__ offd, int* __restrict__ curd,
                               int2* __restrict__ csr) {
    int e = blockIdx.x * 256 + threadIdx.x;
    if (e < N_EDGES) {
        int d = dst[e];
        int pos = offd[d] + atomicAdd(&curd[d], 1);
        csr[pos] = make_int2(src[e], e);
    }
}

// ---------------- node-level precompute, TRANSPOSED: yT[n][o*16+f] ----------------
// yT[n][o*16+f] = bf16( sum_i x[n,i] * Wnn[f*256+i*16+o] ), t[n][o] = x . bnn[:,o]
// Wnn staged in LDS as sW[i*320 + f*20 + o]: f-stride 20 gives bank offsets
// {0,16,0,16} across the 4 fq-groups -> exactly 2 lanes/bank (free, m136).
// 4 nodes per wave share each ds_read (1 read feeds 4 FMAs).
#define YW_F 20
#define YW_I 320   // 16*YW_F
__global__ __launch_bounds__(256) void y_kernel(const float* __restrict__ x,
                                                const float* __restrict__ Wnn,
                                                const float* __restrict__ bnn,
                                                unsigned short* __restrict__ yT,
                                                float* __restrict__ t_arr) {
    __shared__ float sW[16 * YW_I];
    __shared__ float sB[256];
    const int tid = threadIdx.x;
#pragma unroll
    for (int k = 0; k < 4; ++k) {
        float4 w4 = ((const float4*)Wnn)[tid + k * 256];
        int fi = (tid >> 6) + 4 * k;
        int ii = (tid >> 2) & 15;
        int oo = (tid & 3) * 4;
        *(float4*)&sW[ii * YW_I + fi * YW_F + oo] = w4;
    }
    if (tid < 64) *(float4*)&sB[tid * 4] = ((const float4*)bnn)[tid];
    __syncthreads();

    const int lane = tid & 63;
    const int wid = tid >> 6;
    const int n0 = blockIdx.x * 16 + wid * 4;   // 16 nodes/block, 4 per wave (50000 = 3125*16)
    const int o = lane >> 2;
    const int fq = (lane & 3) * 4;

    float xv[4][16];
#pragma unroll
    for (int nd = 0; nd < 4; ++nd) {
        const float* xr = x + (size_t)(n0 + nd) * 16;
#pragma unroll
        for (int q = 0; q < 4; ++q) {
            float4 x4 = *(const float4*)(xr + q * 4);
            xv[nd][4 * q + 0] = x4.x; xv[nd][4 * q + 1] = x4.y;
            xv[nd][4 * q + 2] = x4.z; xv[nd][4 * q + 3] = x4.w;
        }
    }
    float acc[4][4];
#pragma unroll
    for (int j = 0; j < 4; ++j)
#pragma unroll
        for (int nd = 0; nd < 4; ++nd) acc[j][nd] = 0.f;
#pragma unroll
    for (int i = 0; i < 16; ++i) {
#pragma unroll
        for (int j = 0; j < 4; ++j) {
            float w = sW[i * YW_I + (fq + j) * YW_F + o];
#pragma unroll
            for (int nd = 0; nd < 4; ++nd)
                acc[j][nd] = fmaf(xv[nd][i], w, acc[j][nd]);
        }
    }
#pragma unroll
    for (int nd = 0; nd < 4; ++nd) {
        ushort4 o4;
        o4.x = f2bf(acc[0][nd]); o4.y = f2bf(acc[1][nd]);
        o4.z = f2bf(acc[2][nd]); o4.w = f2bf(acc[3][nd]);
        *(ushort4*)(yT + (size_t)(n0 + nd) * 256 + o * 16 + fq) = o4;
    }
    if ((lane & 3) == 0) {
#pragma unroll
        for (int nd = 0; nd < 4; ++nd) {
            float tv = 0.f;
#pragma unroll
            for (int i = 0; i < 16; ++i) tv = fmaf(xv[nd][i], sB[i * 16 + o], tv);
            t_arr[(size_t)(n0 + nd) * 16 + o] = tv;
        }
    }
}

// ---------------- fused NNConv aggregate + root + relu + GAT projection ----------------
__global__ __launch_bounds__(256) void fused_kernel(
    const float* __restrict__ x, const unsigned short* __restrict__ yT,
    const float* __restrict__ t_arr, const float* __restrict__ ea,
    const int2* __restrict__ csr, const int* __restrict__ offd,
    const float* __restrict__ Wroot, const float* __restrict__ becc,
    const float* __restrict__ Wgat, const float* __restrict__ asrc,
    const float* __restrict__ adst,
    unsigned short* __restrict__ z_bf, float* __restrict__ es, float* __restrict__ ed)
{
    const int wid = threadIdx.x >> 6, lane = threadIdx.x & 63;
    const int n = blockIdx.x * 4 + wid;
    if (n >= N_NODES) return;
    const int o = lane & 15, sub = lane >> 4;
    const int beg = offd[n], end = offd[n + 1];
    float acc = 0.f;
    for (int base = beg; base < end; base += 64) {
        int cnt = min(end - base, 64);
        int2 pr = make_int2(0, 0);
        if (lane < cnt) pr = csr[base + lane];
        for (int idx0 = 0; idx0 < cnt; idx0 += 4) {
            int idx = idx0 + sub;                 // uniform within 16-lane sub-group
            int s   = __shfl(pr.x, idx, 64);
            int eid = __shfl(pr.y, idx, 64);
            bool v = idx < cnt;
            float av = v ? ea[(size_t)eid * 16 + o] : 0.f;
            float tv = v ? t_arr[(size_t)s * 16 + o] : 0.f;
            const unsigned short* yp = yT + (size_t)s * 256 + o * 16;
            uint4 r0 = *(const uint4*)yp;
            uint4 r1 = *(const uint4*)(yp + 8);
            float yv[16];
            yv[0]  = bf2f_lo(r0.x); yv[1]  = bf2f_hi(r0.x);
            yv[2]  = bf2f_lo(r0.y); yv[3]  = bf2f_hi(r0.y);
            yv[4]  = bf2f_lo(r0.z); yv[5]  = bf2f_hi(r0.z);
            yv[6]  = bf2f_lo(r0.w); yv[7]  = bf2f_hi(r0.w);
            yv[8]  = bf2f_lo(r1.x); yv[9]  = bf2f_hi(r1.x);
            yv[10] = bf2f_lo(r1.y); yv[11] = bf2f_hi(r1.y);
            yv[12] = bf2f_lo(r1.z); yv[13] = bf2f_hi(r1.z);
            yv[14] = bf2f_lo(r1.w); yv[15] = bf2f_hi(r1.w);
            float m = tv;
#pragma unroll
            for (int f = 0; f < 16; ++f)
                m = fmaf(__shfl(av, (lane & 48) + f, 64), yv[f], m);
            acc += m;
        }
    }
    acc += __shfl_xor(acc, 16, 64);
    acc += __shfl_xor(acc, 32, 64);
    const float* xr = x + (size_t)n * 16;
    float r = becc[o];
#pragma unroll
    for (int i = 0; i < 16; ++i) r = fmaf(xr[i], Wroot[i * 16 + o], r);
    float hval = fmaxf(acc + r, 0.f);
    float z0 = 0.f, z1 = 0.f;
#pragma unroll
    for (int i = 0; i < 16; ++i) {
        float hv = __shfl(hval, (lane & 48) + i, 64);
        z0 = fmaf(hv, Wgat[i * 128 + lane], z0);
        z1 = fmaf(hv, Wgat[i * 128 + 64 + lane], z1);
    }
    z_bf[(size_t)n * 128 + lane] = f2bf(z0);
    z_bf[(size_t)n * 128 + 64 + lane] = f2bf(z1);
    float p0s = z0 * asrc[lane], p1s = z1 * asrc[lane + 64];
    float p0d = z0 * adst[lane], p1d = z1 * adst[lane + 64];
#pragma unroll
    for (int k = 1; k <= 16; k <<= 1) {
        p0s += __shfl_xor(p0s, k, 64);
        p1s += __shfl_xor(p1s, k, 64);
        p0d += __shfl_xor(p0d, k, 64);
        p1d += __shfl_xor(p1d, k, 64);
    }
    if ((lane & 31) == 0) {
        int hh = lane >> 5;
        es[(size_t)n * 4 + hh]     = p0s;
        es[(size_t)n * 4 + hh + 2] = p1s;
        ed[(size_t)n * 4 + hh]     = p0d;
        ed[(size_t)n * 4 + hh + 2] = p1d;
    }
}

// ---------------- GAT aggregation + bias + relu + final fc (8-wide MLP) ----------------
__global__ void gat_kernel(const unsigned short* __restrict__ z_bf, const float* __restrict__ es,
                           const float* __restrict__ ed, const int2* __restrict__ csr,
                           const int* __restrict__ offd,
                           const float* __restrict__ bgat, const float* __restrict__ Wfc,
                           const float* __restrict__ bfc, float* __restrict__ out) {
    int wid = threadIdx.x >> 6;
    int lane = threadIdx.x & 63;
    int n = blockIdx.x * 4 + wid;
    if (n >= N_NODES) return;
    int head = lane >> 4;
    float edh = ed[(size_t)n * 4 + head];
    int beg = offd[n], end = offd[n + 1];
    int deg = end - beg;
    float den = 0.f, a0 = 0.f, a1 = 0.f;
    int s_l = (lane < deg) ? csr[beg + lane].x : 0;
    int m64 = min(deg, 64);
    int el = 0;
    for (; el + 8 <= m64; el += 8) {
        int ss[8]; float w[8]; ushort2 zz[8];
#pragma unroll
        for (int q = 0; q < 8; ++q) ss[q] = __shfl(s_l, el + q, 64);
#pragma unroll
        for (int q = 0; q < 8; ++q) {
            float l = es[(size_t)ss[q] * 4 + head] + edh;
            l = (l > 0.f) ? l : 0.2f * l;
            w[q] = __expf(l);
        }
#pragma unroll
        for (int q = 0; q < 8; ++q)
            zz[q] = *(const ushort2*)(z_bf + (size_t)ss[q] * 128 + 2 * lane);
#pragma unroll
        for (int q = 0; q < 8; ++q) {
            den += w[q];
            a0 = fmaf(w[q], bf2f(zz[q].x), a0);
            a1 = fmaf(w[q], bf2f(zz[q].y), a1);
        }
    }
    for (; el + 4 <= m64; el += 4) {
        int ss[4]; float w[4]; ushort2 zz[4];
#pragma unroll
        for (int q = 0; q < 4; ++q) ss[q] = __shfl(s_l, el + q, 64);
#pragma unroll
        for (int q = 0; q < 4; ++q) {
            float l = es[(size_t)ss[q] * 4 + head] + edh;
            l = (l > 0.f) ? l : 0.2f * l;
            w[q] = __expf(l);
        }
#pragma unroll
        for (int q = 0; q < 4; ++q)
            zz[q] = *(const ushort2*)(z_bf + (size_t)ss[q] * 128 + 2 * lane);
#pragma unroll
        for (int q = 0; q < 4; ++q) {
            den += w[q];
            a0 = fmaf(w[q], bf2f(zz[q].x), a0);
            a1 = fmaf(w[q], bf2f(zz[q].y), a1);
        }
    }
    for (; el < m64; ++el) {
        int s = __shfl(s_l, el, 64);
        float l = es[(size_t)s * 4 + head] + edh;
        l = (l > 0.f) ? l : 0.2f * l;
        float w = __expf(l);
        den += w;
        ushort2 zv = *(const ushort2*)(z_bf + (size_t)s * 128 + 2 * lane);
        a0 = fmaf(w, bf2f(zv.x), a0);
        a1 = fmaf(w, bf2f(zv.y), a1);
    }
    for (int j = beg + 64; j < end; ++j) {
        int s = csr[j].x;
        float l = es[(size_t)s * 4 + head] + edh;
        l = (l > 0.f) ? l : 0.2f * l;
        float w = __expf(l);
        den += w;
        ushort2 zv = *(const ushort2*)(z_bf + (size_t)s * 128 + 2 * lane);
        a0 = fmaf(w, bf2f(zv.x), a0);
        a1 = fmaf(w, bf2f(zv.y), a1);
    }
    float inv = 1.f / (den + 1e-16f);
    float2 bg = *(const float2*)(bgat + 2 * lane);
    float g0 = fmaxf(fmaf(a0, inv, bg.x), 0.f);
    float g1 = fmaxf(fmaf(a1, inv, bg.y), 0.f);
    float2 wf = *(const float2*)(Wfc + 2 * lane);
    float p = g0 * wf.x + g1 * wf.y;
    for (int k = 32; k > 0; k >>= 1) p += __shfl_down(p, k, 64);
    if (lane == 0) out[n] = p + bfc[0];
}

extern "C" void kernel_launch(void* const* d_in, const int* in_sizes, int n_in,
                              void* d_out, int out_size, void* d_ws, size_t ws_size,
                              hipStream_t stream) {
    const float* x     = (const float*)d_in[0];
    const int*   eidx  = (const int*)d_in[1];
    const float* ea    = (const float*)d_in[2];
    const float* Wnn   = (const float*)d_in[3];
    const float* bnn   = (const float*)d_in[4];
    const float* Wroot = (const float*)d_in[5];
    const float* becc  = (const float*)d_in[6];
    const float* Wgat  = (const float*)d_in[7];
    const float* asrc  = (const float*)d_in[8];
    const float* adst  = (const float*)d_in[9];
    const float* bgat  = (const float*)d_in[10];
    const float* Wfc   = (const float*)d_in[11];
    const float* bfc   = (const float*)d_in[12];
    const int* src = eidx;
    const int* dst = eidx + N_EDGES;
    float* out = (float*)d_out;

    char* ws = (char*)d_ws;
    size_t off = 0;
    auto alloc = [&](size_t bytes) {
        void* p = ws + off;
        off += (bytes + 255) & ~(size_t)255;
        return p;
    };
    int*  cd   = (int*)alloc((size_t)N_NODES * 4);
    int*  curd = (int*)alloc((size_t)N_NODES * 4);
    int*  offd = (int*)alloc((size_t)(N_NODES + 1) * 4);
    int2* csr  = (int2*)alloc((size_t)N_EDGES * 8);
    unsigned short* yT = (unsigned short*)alloc((size_t)N_NODES * 256 * 2);
    float* t_arr = (float*)alloc((size_t)N_NODES * 16 * 4);
    unsigned short* z_bf = (unsigned short*)alloc((size_t)N_NODES * 128 * 2);
    float* es = (float*)alloc((size_t)N_NODES * 4 * 4);
    float* ed = (float*)alloc((size_t)N_NODES * 4 * 4);

    hipMemsetAsync(cd, 0, (size_t)N_NODES * 4, stream);
    hipMemsetAsync(curd, 0, (size_t)N_NODES * 4, stream);

    int eb = (N_EDGES + 255) / 256;
    count_kernel<<<eb, 256, 0, stream>>>(dst, cd);
    scan_kernel<<<1, 1024, 0, stream>>>(cd, offd);
    scatter_kernel<<<eb, 256, 0, stream>>>(src, dst, offd, curd, csr);
    y_kernel<<<3125, 256, 0, stream>>>(x, Wnn, bnn, yT, t_arr);
    fused_kernel<<<(N_NODES + 3) / 4, 256, 0, stream>>>(x, yT, t_arr, ea, csr, offd,
                                                        Wroot, becc, Wgat, asrc, adst,
                                                        z_bf, es, ed);
    gat_kernel<<<(N_NODES + 3) / 4, 256, 0, stream>>>(z_bf, es, ed, csr, offd,
                                                      bgat, Wfc, bfc, out);
}